// Round 14
// baseline (143.701 us; speedup 1.0000x reference)
//
#include <hip/hip_runtime.h>
#include <cmath>

#define BATCH 8
#define SEQ   2048
#define NEMB  2048
#define HD    128
#define NROWS (BATCH * SEQ)   // 16384

typedef __bf16 v8bf __attribute__((ext_vector_type(8)));
typedef float  f32x4 __attribute__((ext_vector_type(4)));

union U8 { v8bf v; __bf16 b[8]; unsigned short e[8]; };

__device__ inline void async16(void* lds, const void* g) {
  __builtin_amdgcn_global_load_lds(
      (const __attribute__((address_space(1))) unsigned int*)g,
      (__attribute__((address_space(3))) unsigned int*)lds, 16, 0, 0);
}

__device__ inline v8bf cvt8(float4 a, float4 b) {
  U8 u;
  u.b[0] = (__bf16)a.x; u.b[1] = (__bf16)a.y; u.b[2] = (__bf16)a.z; u.b[3] = (__bf16)a.w;
  u.b[4] = (__bf16)b.x; u.b[5] = (__bf16)b.y; u.b[6] = (__bf16)b.z; u.b[7] = (__bf16)b.w;
  return u.v;
}

// ---------------- x fp32 -> bf16, MFMA-A-fragment packed ----------------
// unit u = ((mt*32 + tt)*4 + fm)*2 + kk  (1 KB each, 64 lanes x 16B)
// elem j of (u,lane): x[mt*64 + fm*16 + (lane&15)][tt*64 + kk*32 + (lane>>4)*8 + j]
__global__ __launch_bounds__(256) void xpack_kernel(
    const float* __restrict__ x, __bf16* __restrict__ xp) {
  const int g = blockIdx.x * 256 + threadIdx.x;   // 16384 blocks
  const int lane = g & 63;
  const int u = g >> 6;              // 0..65535
  const int kk = u & 1;
  const int fm = (u >> 1) & 3;
  const int tt = (u >> 3) & 31;
  const int mt = u >> 8;
  const int row = mt * 64 + fm * 16 + (lane & 15);
  const int k   = tt * 64 + kk * 32 + (lane >> 4) * 8;
  const float4* s = (const float4*)(x + (size_t)row * NEMB + k);
  float4 f0 = s[0], f1 = s[1];
  *(v8bf*)(xp + (size_t)g * 8) = cvt8(f0, f1);
}

// ---------------- W fp32 -> bf16, MFMA-B-fragment packed ----------------
// unit u = ((p*8 + nf)*32 + tt)*2 + kk
// elem j: W[p][nf*16 + (lane&15)][tt*64 + kk*32 + (lane>>4)*8 + j]
__global__ __launch_bounds__(256) void wpack_kernel(
    const float* __restrict__ Wq, const float* __restrict__ Wk,
    const float* __restrict__ Wv, __bf16* __restrict__ wp) {
  const int g = blockIdx.x * 256 + threadIdx.x;   // 384 blocks
  const int lane = g & 63;
  const int u = g >> 6;              // 0..1535
  const int kk = u & 1;
  const int tt = (u >> 1) & 31;
  const int nf = (u >> 6) & 7;
  const int p  = u >> 9;
  const float* __restrict__ W = p == 0 ? Wq : p == 1 ? Wk : Wv;
  const int row = nf * 16 + (lane & 15);
  const int k   = tt * 64 + kk * 32 + (lane >> 4) * 8;
  const float4* s = (const float4*)(W + (size_t)row * NEMB + k);
  float4 f0 = s[0], f1 = s[1];
  *(v8bf*)(wp + (size_t)g * 8) = cvt8(f0, f1);
}

// ---------------- QKV projection: register-direct, no LDS, no barriers ---
// grid 768 (mt-major XCD-chunked: 3 proj blocks of one x-panel share an L2).
// 4 waves (2x2), wave = 32(M)x64(N). All operand loads are 1KB bursts from
// fragment-packed xp/wp; depth-1 named-register pipeline; waves free-run.
__global__ __launch_bounds__(256) void qkv_proj_kernel(
    const __bf16* __restrict__ xp, const __bf16* __restrict__ wp,
    const float* __restrict__ bq, const float* __restrict__ bk,
    const float* __restrict__ bv,
    __bf16* __restrict__ Qb, __bf16* __restrict__ Kb, __bf16* __restrict__ Vb)
{
  const int bid0 = blockIdx.x;
  const int bid = ((bid0 & 7) * 96) + (bid0 >> 3);   // 768 % 8 == 0
  const int mt = bid / 3;
  const int proj = bid % 3;
  const float* __restrict__ bias = proj == 0 ? bq : proj == 1 ? bk : bv;
  __bf16* __restrict__ Out = proj == 0 ? Qb : proj == 1 ? Kb : Vb;

  const int t = threadIdx.x, lane = t & 63, w = t >> 6;
  const int wm = w >> 1, wn = w & 1;
  const int hi = lane >> 4, lo = lane & 15;

  // per-wave operand bases (bf16 elements)
  const __bf16* abase = xp + (size_t)(mt * 32) * 4096 + lane * 8;  // + (tt*8 + fm*2 + kk)*512
  const __bf16* bbase = wp + (size_t)(proj * 8 + wn * 4) * 32768 + lane * 8; // + (n*64 + tt*2 + kk)*512

  f32x4 acc[2][4];
  const f32x4 fz = {0.f, 0.f, 0.f, 0.f};
#pragma unroll
  for (int m = 0; m < 2; ++m)
#pragma unroll
    for (int n = 0; n < 4; ++n) acc[m][n] = fz;

  v8bf A0[2][2], A1[2][2];   // [m][kk]
  v8bf B0[4][2], B1[4][2];   // [n][kk]

  auto LD = [&](v8bf (&A)[2][2], v8bf (&B)[4][2], int tt) {
#pragma unroll
    for (int m = 0; m < 2; ++m)
#pragma unroll
      for (int kk = 0; kk < 2; ++kk)
        A[m][kk] = *(const v8bf*)(abase + (size_t)(tt * 8 + (wm * 2 + m) * 2 + kk) * 512);
#pragma unroll
    for (int n = 0; n < 4; ++n)
#pragma unroll
      for (int kk = 0; kk < 2; ++kk)
        B[n][kk] = *(const v8bf*)(bbase + (size_t)(n * 64 + tt * 2 + kk) * 512);
  };
  auto STEP = [&](v8bf (&A)[2][2], v8bf (&B)[4][2]) {
#pragma unroll
    for (int kk = 0; kk < 2; ++kk)
#pragma unroll
      for (int m = 0; m < 2; ++m)
#pragma unroll
        for (int n = 0; n < 4; ++n)
          acc[m][n] = __builtin_amdgcn_mfma_f32_16x16x32_bf16(A[m][kk], B[n][kk], acc[m][n], 0, 0, 0);
  };

  const int NT = NEMB / 64;  // 32 (even)
  LD(A0, B0, 0);
  for (int tt = 0; tt < NT; tt += 2) {
    LD(A1, B1, tt + 1);                  // issue odd-step loads
    STEP(A0, B0);                        // compute even step
    if (tt + 2 < NT) LD(A0, B0, tt + 2); // issue next even-step loads
    STEP(A1, B1);                        // compute odd step
  }

#pragma unroll
  for (int n = 0; n < 4; ++n) {
    const int col = wn * 64 + n * 16 + lo;
    const float bi = bias[col];
#pragma unroll
    for (int m = 0; m < 2; ++m) {
#pragma unroll
      for (int r = 0; r < 4; ++r) {
        const int row = mt * 64 + wm * 32 + m * 16 + hi * 4 + r;
        Out[(size_t)row * HD + col] = (__bf16)(acc[m][n][r] + bi);
      }
    }
  }
}

// ---------------- Flash attention, split-KV x4 ----------------
// grid: 8 batches * 32 q-tiles * 4 kv-chunks = 1024 blocks, 256 thr.
__global__ __launch_bounds__(256) void attn_kernel(
    const __bf16* __restrict__ Qb, const __bf16* __restrict__ Kb,
    const __bf16* __restrict__ Vb, __bf16* __restrict__ Opart,
    float* __restrict__ Ml)
{
  const int bid0 = blockIdx.x;
  const int bid = ((bid0 & 7) << 7) + (bid0 >> 3);   // one batch per XCD
  const int b = bid >> 7;
  const int q = bid & 127;
  const int qt = q >> 2;
  const int s  = q & 3;
  const int q0 = qt * 64;
  const int kv_beg = (s * (qt + 1)) >> 2;
  const int kv_end = ((s + 1) * (qt + 1)) >> 2;
  const int nst = kv_end - kv_beg;

  const int t = threadIdx.x, lane = t & 63, w = t >> 6;
  const int hi = lane >> 4, lo = lane & 15;

  __shared__ __bf16 Ksm[2][64 * 128];   // [key][d], 256B rows, swizzled
  __shared__ __bf16 Vtsm[2][128 * 64];  // [d][key], 128B rows, swizzled
  __shared__ __bf16 Psm[4][16 * 64];    // per-wave P, swizzled

  v8bf aQ[4];
  {
    const __bf16* qp = Qb + ((size_t)(b * SEQ + q0 + w * 16 + lo)) * HD + hi * 8;
#pragma unroll
    for (int kk = 0; kk < 4; ++kk) aQ[kk] = *(const v8bf*)(qp + kk * 32);
  }

  const __bf16* kga[4];
#pragma unroll
  for (int i = 0; i < 4; ++i) {
    const int r = (w * 4 + i) * 4 + (lane >> 4);   // key row 0..63
    const int c = (lane & 15) ^ (r & 7);           // 16B chunk within 256B row
    kga[i] = Kb + ((size_t)(b * SEQ) + r) * HD + c * 8;
  }

  const int keyg = t >> 4, dg = t & 15;   // keys keyg*4.., d-cols dg*8..
  U8 vv[4];

  f32x4 accO[8];
  const f32x4 fz = {0.f, 0.f, 0.f, 0.f};
#pragma unroll
  for (int n = 0; n < 8; ++n) accO[n] = fz;
  float m_s[4], l_s[4];
#pragma unroll
  for (int r = 0; r < 4; ++r) { m_s[r] = -INFINITY; l_s[r] = 0.f; }

  const float scale = 0.022097086912079608f;  // 1/sqrt(2048)

  if (nst > 0) {
    auto STAGE_K = [&](int kv, int buf) {
      const size_t off = (size_t)kv * 64 * HD;
      char* kb = (char*)&Ksm[buf][0];
#pragma unroll
      for (int i = 0; i < 4; ++i) async16(kb + (w * 4 + i) * 1024, kga[i] + off);
    };
    auto LOAD_V = [&](int kv) {
      const __bf16* vp = Vb + ((size_t)(b * SEQ + kv * 64 + keyg * 4)) * HD + dg * 8;
#pragma unroll
      for (int j = 0; j < 4; ++j) vv[j].v = *(const v8bf*)(vp + (size_t)j * HD);
    };
    auto WRITE_VT = [&](int buf) {
      char* vb2 = (char*)&Vtsm[buf][0];
#pragma unroll
      for (int dd = 0; dd < 8; ++dd) {
        const int d = (dd + dg) & 7;               // rotation: row&7 spans lanes
        ushort4 pk = make_ushort4(vv[0].e[d], vv[1].e[d], vv[2].e[d], vv[3].e[d]);
        const int row = dg * 8 + d;
        *(ushort4*)(vb2 + row * 128 + ((keyg * 8) ^ ((row & 7) << 4))) = pk;
      }
    };

    STAGE_K(kv_beg, 0);
    LOAD_V(kv_beg);
    WRITE_VT(0);
    __syncthreads();   // K DMA drained + Vt visible

    for (int t2 = 0; t2 < nst; ++t2) {
      const int kv = kv_beg + t2;
      const int cur = t2 & 1;
      const bool more = (t2 + 1 < nst);
      if (more) { STAGE_K(kv + 1, cur ^ 1); LOAD_V(kv + 1); }

      // S = Q K^T
      f32x4 accS[4];
#pragma unroll
      for (int n = 0; n < 4; ++n) accS[n] = fz;
      const char* ksm = (const char*)&Ksm[cur][0];
#pragma unroll
      for (int kk = 0; kk < 4; ++kk) {
        const int cb = kk * 64 + hi * 16;
        v8bf bk[4];
#pragma unroll
        for (int n = 0; n < 4; ++n) {
          const int r = n * 16 + lo;
          bk[n] = *(const v8bf*)(ksm + r * 256 + (cb ^ ((r & 7) << 4)));
        }
#pragma unroll
        for (int n = 0; n < 4; ++n)
          accS[n] = __builtin_amdgcn_mfma_f32_16x16x32_bf16(aQ[kk], bk[n], accS[n], 0, 0, 0);
      }

      float sv[4][4];
      const bool diag = (kv == qt);
#pragma unroll
      for (int n = 0; n < 4; ++n)
#pragma unroll
        for (int r = 0; r < 4; ++r) {
          float v = accS[n][r] * scale;
          if (diag) {
            const int key = kv * 64 + n * 16 + lo;
            const int qr = q0 + w * 16 + hi * 4 + r;
            if (key > qr) v = -INFINITY;
          }
          sv[n][r] = v;
        }

      float mx[4];
#pragma unroll
      for (int r = 0; r < 4; ++r) {
        mx[r] = fmaxf(fmaxf(sv[0][r], sv[1][r]), fmaxf(sv[2][r], sv[3][r]));
#pragma unroll
        for (int off = 1; off < 16; off <<= 1)
          mx[r] = fmaxf(mx[r], __shfl_xor(mx[r], off));
      }
      float corr[4], p[4][4], rs[4];
#pragma unroll
      for (int r = 0; r < 4; ++r) {
        const float mnew = fmaxf(m_s[r], mx[r]);
        corr[r] = __expf(m_s[r] - mnew);
        m_s[r] = mnew;
        rs[r] = 0.f;
      }
#pragma unroll
      for (int n = 0; n < 4; ++n)
#pragma unroll
        for (int r = 0; r < 4; ++r) {
          p[n][r] = __expf(sv[n][r] - m_s[r]);
          rs[r] += p[n][r];
        }
#pragma unroll
      for (int r = 0; r < 4; ++r) {
#pragma unroll
        for (int off = 1; off < 16; off <<= 1) rs[r] += __shfl_xor(rs[r], off);
        l_s[r] = l_s[r] * corr[r] + rs[r];
      }
#pragma unroll
      for (int n = 0; n < 8; ++n)
#pragma unroll
        for (int r = 0; r < 4; ++r) accO[n][r] *= corr[r];

#pragma unroll
      for (int n = 0; n < 4; ++n)
#pragma unroll
        for (int r = 0; r < 4; ++r) {
          const int row = hi * 4 + r;
          __bf16 h = (__bf16)p[n][r];
          *(unsigned short*)((char*)&Psm[w][0] + row * 128 +
                             (((n * 16 + lo) * 2) ^ ((row & 7) << 4))) =
              __builtin_bit_cast(unsigned short, h);
        }

      if (more) WRITE_VT(cur ^ 1);

      const char* vsm = (const char*)&Vtsm[cur][0];
#pragma unroll
      for (int k2 = 0; k2 < 2; ++k2) {
        const int cb = k2 * 64 + hi * 16;
        const v8bf aP = *(const v8bf*)((const char*)&Psm[w][0] + lo * 128 + (cb ^ ((lo & 7) << 4)));
#pragma unroll
        for (int n = 0; n < 8; ++n) {
          const int r = n * 16 + lo;
          const v8bf bv = *(const v8bf*)(vsm + r * 128 + (cb ^ ((r & 7) << 4)));
          accO[n] = __builtin_amdgcn_mfma_f32_16x16x32_bf16(aP, bv, accO[n], 0, 0, 0);
        }
      }
      if (more) __syncthreads();
    }
  }

  // store partials: unnormalized O (bf16), m, l
#pragma unroll
  for (int r = 0; r < 4; ++r) {
    const int qr = q0 + w * 16 + hi * 4 + r;
    __bf16* op = Opart + ((size_t)s * NROWS + b * SEQ + qr) * HD + lo;
#pragma unroll
    for (int n = 0; n < 8; ++n) op[n * 16] = (__bf16)accO[n][r];
    if (lo == 0) {
      float* mlp = Ml + ((size_t)s * NROWS + b * SEQ + qr) * 2;
      mlp[0] = m_s[r];
      mlp[1] = l_s[r];
    }
  }
}

// ---------------- combine the four KV-chunk partials ----------------
__global__ __launch_bounds__(256) void combine_kernel(
    const __bf16* __restrict__ Opart, const float* __restrict__ Ml,
    float* __restrict__ out)
{
  const int idx = blockIdx.x * 256 + threadIdx.x;  // 0..65535
  const int row = idx >> 2, ch = idx & 3;          // 32-col chunk
  float m[4], l[4];
#pragma unroll
  for (int s = 0; s < 4; ++s) {
    const float* mlp = Ml + ((size_t)s * NROWS + row) * 2;
    m[s] = mlp[0];
    l[s] = mlp[1];
  }
  const float M = fmaxf(fmaxf(m[0], m[1]), fmaxf(m[2], m[3]));
  float e[4], denom = 0.f;
#pragma unroll
  for (int s = 0; s < 4; ++s) { e[s] = __expf(m[s] - M); denom += l[s] * e[s]; }
  const float inv = 1.f / denom;

  float* po = out + (size_t)row * HD + ch * 32;
#pragma unroll
  for (int j = 0; j < 4; ++j) {     // 4 groups of 8 cols
    float sum[8];
#pragma unroll
    for (int q2 = 0; q2 < 8; ++q2) sum[q2] = 0.f;
#pragma unroll
    for (int s = 0; s < 4; ++s) {
      U8 o;
      o.v = *(const v8bf*)(Opart + ((size_t)s * NROWS + row) * HD + ch * 32 + j * 8);
#pragma unroll
      for (int q2 = 0; q2 < 8; ++q2) sum[q2] += (float)o.b[q2] * e[s];
    }
#pragma unroll
    for (int q2 = 0; q2 < 8; ++q2) po[j * 8 + q2] = sum[q2] * inv;
  }
}

extern "C" void kernel_launch(void* const* d_in, const int* in_sizes, int n_in,
                              void* d_out, int out_size, void* d_ws, size_t ws_size,
                              hipStream_t stream) {
  const float* x  = (const float*)d_in[0];
  const float* Wq = (const float*)d_in[1];
  const float* bq = (const float*)d_in[2];
  const float* Wk = (const float*)d_in[3];
  const float* bk = (const float*)d_in[4];
  const float* Wv = (const float*)d_in[5];
  const float* bv = (const float*)d_in[6];
  float* out = (float*)d_out;

  // workspace (~94 MiB)
  __bf16* Qb = (__bf16*)d_ws;                        // 16384x128 bf16 each
  __bf16* Kb = Qb + (size_t)NROWS * HD;
  __bf16* Vb = Kb + (size_t)NROWS * HD;
  __bf16* Wp = Vb + (size_t)NROWS * HD;              // 1536 x 512 bf16 = 1.5 MB
  __bf16* Xp = Wp + (size_t)1536 * 512;              // 65536 x 512 bf16 = 64 MB
  __bf16* Opart = Xp + (size_t)65536 * 512;          // 4 x 16384 x 128 bf16
  float*  Ml = (float*)(Opart + (size_t)4 * NROWS * HD);  // 4 x 16384 x 2 fp32

  wpack_kernel<<<dim3(384), dim3(256), 0, stream>>>(Wq, Wk, Wv, Wp);
  xpack_kernel<<<dim3(16384), dim3(256), 0, stream>>>(x, Xp);
  qkv_proj_kernel<<<dim3(256 * 3), dim3(256), 0, stream>>>(
      Xp, Wp, bq, bk, bv, Qb, Kb, Vb);
  attn_kernel<<<dim3(BATCH * 32 * 4), dim3(256), 0, stream>>>(Qb, Kb, Vb, Opart, Ml);
  combine_kernel<<<dim3(NROWS * 4 / 256), dim3(256), 0, stream>>>(Opart, Ml, out);
}

// Round 15
// 116.767 us; speedup vs baseline: 1.2307x; 1.2307x over previous
//
#include <hip/hip_runtime.h>
#include <cmath>

#define BATCH 8
#define SEQ   2048
#define NEMB  2048
#define HD    128
#define NROWS (BATCH * SEQ)   // 16384

typedef __bf16 v8bf __attribute__((ext_vector_type(8)));
typedef float  f32x4 __attribute__((ext_vector_type(4)));

union U8 { v8bf v; __bf16 b[8]; unsigned short e[8]; };
union F4 { f32x4 v; float f[4]; };

__device__ inline void async16(void* lds, const void* g) {
  __builtin_amdgcn_global_load_lds(
      (const __attribute__((address_space(1))) unsigned int*)g,
      (__attribute__((address_space(3))) unsigned int*)lds, 16, 0, 0);
}

__device__ inline v8bf cvt8(float4 a, float4 b) {
  U8 u;
  u.b[0] = (__bf16)a.x; u.b[1] = (__bf16)a.y; u.b[2] = (__bf16)a.z; u.b[3] = (__bf16)a.w;
  u.b[4] = (__bf16)b.x; u.b[5] = (__bf16)b.y; u.b[6] = (__bf16)b.z; u.b[7] = (__bf16)b.w;
  return u.v;
}

// ---------------- W fp32 -> bf16 (3 x 128 x 2048) ----------------
__global__ __launch_bounds__(256) void wconv_kernel(
    const float* __restrict__ Wq, const float* __restrict__ Wk,
    const float* __restrict__ Wv, __bf16* __restrict__ out) {
  const int id = blockIdx.x;                 // 3 * 64 blocks
  const int proj = id >> 6, blk = id & 63;
  const float* __restrict__ W = proj == 0 ? Wq : proj == 1 ? Wk : Wv;
  __bf16* __restrict__ o = out + (size_t)proj * (HD * NEMB);
  const int base = blk * 4096 + threadIdx.x * 16;
  const float4* s = (const float4*)(W + base);
  float4 f0 = s[0], f1 = s[1], f2 = s[2], f3 = s[3];
  *(v8bf*)(o + base) = cvt8(f0, f1);
  *(v8bf*)(o + base + 8) = cvt8(f2, f3);
}

// ---------------- QKV projection: m97-style 128x128 tile, 4x4 acc/wave ---
// 4 waves (2x2), each owns 64x64 output (4x4 frags of 16x16x32).
//   A fp32 [128][64] (32 KB) via global_load_lds, cvt->bf16 at frag read.
//   B bf16 [128][64] (16 KB) via global_load_lds.
// Single-buffered (48 KB), 2 barriers/step, 32 steps. grid 384 = 128mt x 3.
__global__ __launch_bounds__(256, 3) void qkv_proj_kernel(
    const float* __restrict__ x, const __bf16* __restrict__ Wb,
    const float* __restrict__ bq, const float* __restrict__ bk,
    const float* __restrict__ bv,
    __bf16* __restrict__ Qb, __bf16* __restrict__ Kb, __bf16* __restrict__ Vb)
{
  const int bid0 = blockIdx.x;
  const int bid = ((bid0 & 7) * 48) + (bid0 >> 3);   // 384 % 8 == 0
  const int mt = bid / 3;
  const int proj = bid % 3;
  const __bf16* __restrict__ W = Wb + (size_t)proj * (HD * NEMB);
  const float* __restrict__ bias = proj == 0 ? bq : proj == 1 ? bk : bv;
  __bf16* __restrict__ Out = proj == 0 ? Qb : proj == 1 ? Kb : Vb;
  const int m0 = mt * 128;

  __shared__ float  Asm[128 * 64];    // fp32 x tile, 256B rows (32 KB)
  __shared__ __bf16 Bsm[128 * 64];    // bf16 W tile, 128B rows (16 KB)

  const int t = threadIdx.x, lane = t & 63, w = t >> 6;
  const int wm = w >> 1, wn = w & 1;            // wave: 64x64 quadrant
  const int hi = lane >> 4, lo = lane & 15;

  // A staging: 32 chunks of 1KB (4 rows x 256B each); 8 chunks/wave
  const float* pa[8];
  char* la[8];
#pragma unroll
  for (int i = 0; i < 8; ++i) {
    const int j = w * 8 + i;
    const int r = j * 4 + (lane >> 4);           // 0..127
    const int c = (lane & 15) ^ (r & 7);         // inverse swizzle
    pa[i] = x + (size_t)(m0 + r) * NEMB + c * 4;
    la[i] = (char*)Asm + j * 1024;
  }
  // B staging: 16 chunks of 1KB (8 rows x 128B each); 4 chunks/wave
  const __bf16* pb[4];
  char* lb[4];
#pragma unroll
  for (int i = 0; i < 4; ++i) {
    const int j = w * 4 + i;
    const int r = j * 8 + (lane >> 3);           // 0..127
    const int c = (lane & 7) ^ (r & 7);
    pb[i] = W + (size_t)r * NEMB + c * 8;
    lb[i] = (char*)Bsm + j * 1024;
  }

  f32x4 acc[4][4];
  const f32x4 fz = {0.f, 0.f, 0.f, 0.f};
#pragma unroll
  for (int m = 0; m < 4; ++m)
#pragma unroll
    for (int n = 0; n < 4; ++n) acc[m][n] = fz;

  for (int tt = 0; tt < NEMB / 64; ++tt) {
    const int k0 = tt * 64;
    __syncthreads();   // previous compute done -> safe to overwrite tiles
#pragma unroll
    for (int i = 0; i < 8; ++i) async16(la[i], pa[i] + k0);
#pragma unroll
    for (int i = 0; i < 4; ++i) async16(lb[i], pb[i] + k0);
    __syncthreads();   // drain: tile tt resident

#pragma unroll
    for (int kk = 0; kk < 2; ++kk) {
      v8bf a[4], b[4];
#pragma unroll
      for (int m = 0; m < 4; ++m) {
        const int r = wm * 64 + m * 16 + lo;
        const int s = kk * 8 + hi * 2;           // fp32 16B-chunk pair
        const char* rowp = (const char*)Asm + r * 256;
        F4 a0, a1;
        a0.v = *(const f32x4*)(rowp + (((s)     ^ (r & 7)) << 4));
        a1.v = *(const f32x4*)(rowp + (((s + 1) ^ (r & 7)) << 4));
        U8 u;
#pragma unroll
        for (int q = 0; q < 4; ++q) {
          u.b[q]     = (__bf16)a0.f[q];
          u.b[q + 4] = (__bf16)a1.f[q];
        }
        a[m] = u.v;
      }
#pragma unroll
      for (int n = 0; n < 4; ++n) {
        const int r = wn * 64 + n * 16 + lo;
        const int kc = kk * 4 + hi;
        b[n] = *(const v8bf*)((const char*)Bsm + r * 128 + ((kc ^ (r & 7)) << 4));
      }
#pragma unroll
      for (int m = 0; m < 4; ++m)
#pragma unroll
        for (int n = 0; n < 4; ++n)
          acc[m][n] = __builtin_amdgcn_mfma_f32_16x16x32_bf16(a[m], b[n], acc[m][n], 0, 0, 0);
    }
  }

#pragma unroll
  for (int n = 0; n < 4; ++n) {
    const int col = wn * 64 + n * 16 + lo;
    const float bi = bias[col];
#pragma unroll
    for (int m = 0; m < 4; ++m) {
#pragma unroll
      for (int r = 0; r < 4; ++r) {
        const int row = m0 + wm * 64 + m * 16 + hi * 4 + r;
        Out[(size_t)row * HD + col] = (__bf16)(acc[m][n][r] + bi);
      }
    }
  }
}

// ---------------- Flash attention, split-KV x4 ----------------
// grid: 8 batches * 32 q-tiles * 4 kv-chunks = 1024 blocks, 256 thr.
__global__ __launch_bounds__(256) void attn_kernel(
    const __bf16* __restrict__ Qb, const __bf16* __restrict__ Kb,
    const __bf16* __restrict__ Vb, __bf16* __restrict__ Opart,
    float* __restrict__ Ml)
{
  const int bid0 = blockIdx.x;
  const int bid = ((bid0 & 7) << 7) + (bid0 >> 3);   // one batch per XCD
  const int b = bid >> 7;
  const int q = bid & 127;
  const int qt = q >> 2;
  const int s  = q & 3;
  const int q0 = qt * 64;
  const int kv_beg = (s * (qt + 1)) >> 2;
  const int kv_end = ((s + 1) * (qt + 1)) >> 2;
  const int nst = kv_end - kv_beg;

  const int t = threadIdx.x, lane = t & 63, w = t >> 6;
  const int hi = lane >> 4, lo = lane & 15;

  __shared__ __bf16 Ksm[2][64 * 128];   // [key][d], 256B rows, swizzled
  __shared__ __bf16 Vtsm[2][128 * 64];  // [d][key], 128B rows, swizzled
  __shared__ __bf16 Psm[4][16 * 64];    // per-wave P, swizzled

  v8bf aQ[4];
  {
    const __bf16* qp = Qb + ((size_t)(b * SEQ + q0 + w * 16 + lo)) * HD + hi * 8;
#pragma unroll
    for (int kk = 0; kk < 4; ++kk) aQ[kk] = *(const v8bf*)(qp + kk * 32);
  }

  const __bf16* kga[4];
#pragma unroll
  for (int i = 0; i < 4; ++i) {
    const int r = (w * 4 + i) * 4 + (lane >> 4);   // key row 0..63
    const int c = (lane & 15) ^ (r & 7);           // 16B chunk within 256B row
    kga[i] = Kb + ((size_t)(b * SEQ) + r) * HD + c * 8;
  }

  const int keyg = t >> 4, dg = t & 15;   // keys keyg*4.., d-cols dg*8..
  U8 vv[4];

  f32x4 accO[8];
  const f32x4 fz = {0.f, 0.f, 0.f, 0.f};
#pragma unroll
  for (int n = 0; n < 8; ++n) accO[n] = fz;
  float m_s[4], l_s[4];
#pragma unroll
  for (int r = 0; r < 4; ++r) { m_s[r] = -INFINITY; l_s[r] = 0.f; }

  const float scale = 0.022097086912079608f;  // 1/sqrt(2048)

  if (nst > 0) {
    auto STAGE_K = [&](int kv, int buf) {
      const size_t off = (size_t)kv * 64 * HD;
      char* kb = (char*)&Ksm[buf][0];
#pragma unroll
      for (int i = 0; i < 4; ++i) async16(kb + (w * 4 + i) * 1024, kga[i] + off);
    };
    auto LOAD_V = [&](int kv) {
      const __bf16* vp = Vb + ((size_t)(b * SEQ + kv * 64 + keyg * 4)) * HD + dg * 8;
#pragma unroll
      for (int j = 0; j < 4; ++j) vv[j].v = *(const v8bf*)(vp + (size_t)j * HD);
    };
    auto WRITE_VT = [&](int buf) {
      char* vb2 = (char*)&Vtsm[buf][0];
#pragma unroll
      for (int dd = 0; dd < 8; ++dd) {
        const int d = (dd + dg) & 7;               // rotation: row&7 spans lanes
        ushort4 pk = make_ushort4(vv[0].e[d], vv[1].e[d], vv[2].e[d], vv[3].e[d]);
        const int row = dg * 8 + d;
        *(ushort4*)(vb2 + row * 128 + ((keyg * 8) ^ ((row & 7) << 4))) = pk;
      }
    };

    STAGE_K(kv_beg, 0);
    LOAD_V(kv_beg);
    WRITE_VT(0);
    __syncthreads();   // K DMA drained + Vt visible

    for (int t2 = 0; t2 < nst; ++t2) {
      const int kv = kv_beg + t2;
      const int cur = t2 & 1;
      const bool more = (t2 + 1 < nst);
      if (more) { STAGE_K(kv + 1, cur ^ 1); LOAD_V(kv + 1); }

      // S = Q K^T
      f32x4 accS[4];
#pragma unroll
      for (int n = 0; n < 4; ++n) accS[n] = fz;
      const char* ksm = (const char*)&Ksm[cur][0];
#pragma unroll
      for (int kk = 0; kk < 4; ++kk) {
        const int cb = kk * 64 + hi * 16;
        v8bf bk[4];
#pragma unroll
        for (int n = 0; n < 4; ++n) {
          const int r = n * 16 + lo;
          bk[n] = *(const v8bf*)(ksm + r * 256 + (cb ^ ((r & 7) << 4)));
        }
#pragma unroll
        for (int n = 0; n < 4; ++n)
          accS[n] = __builtin_amdgcn_mfma_f32_16x16x32_bf16(aQ[kk], bk[n], accS[n], 0, 0, 0);
      }

      float sv[4][4];
      const bool diag = (kv == qt);
#pragma unroll
      for (int n = 0; n < 4; ++n)
#pragma unroll
        for (int r = 0; r < 4; ++r) {
          float v = accS[n][r] * scale;
          if (diag) {
            const int key = kv * 64 + n * 16 + lo;
            const int qr = q0 + w * 16 + hi * 4 + r;
            if (key > qr) v = -INFINITY;
          }
          sv[n][r] = v;
        }

      float mx[4];
#pragma unroll
      for (int r = 0; r < 4; ++r) {
        mx[r] = fmaxf(fmaxf(sv[0][r], sv[1][r]), fmaxf(sv[2][r], sv[3][r]));
#pragma unroll
        for (int off = 1; off < 16; off <<= 1)
          mx[r] = fmaxf(mx[r], __shfl_xor(mx[r], off));
      }
      float corr[4], p[4][4], rs[4];
#pragma unroll
      for (int r = 0; r < 4; ++r) {
        const float mnew = fmaxf(m_s[r], mx[r]);
        corr[r] = __expf(m_s[r] - mnew);
        m_s[r] = mnew;
        rs[r] = 0.f;
      }
#pragma unroll
      for (int n = 0; n < 4; ++n)
#pragma unroll
        for (int r = 0; r < 4; ++r) {
          p[n][r] = __expf(sv[n][r] - m_s[r]);
          rs[r] += p[n][r];
        }
#pragma unroll
      for (int r = 0; r < 4; ++r) {
#pragma unroll
        for (int off = 1; off < 16; off <<= 1) rs[r] += __shfl_xor(rs[r], off);
        l_s[r] = l_s[r] * corr[r] + rs[r];
      }
#pragma unroll
      for (int n = 0; n < 8; ++n)
#pragma unroll
        for (int r = 0; r < 4; ++r) accO[n][r] *= corr[r];

#pragma unroll
      for (int n = 0; n < 4; ++n)
#pragma unroll
        for (int r = 0; r < 4; ++r) {
          const int row = hi * 4 + r;
          __bf16 h = (__bf16)p[n][r];
          *(unsigned short*)((char*)&Psm[w][0] + row * 128 +
                             (((n * 16 + lo) * 2) ^ ((row & 7) << 4))) =
              __builtin_bit_cast(unsigned short, h);
        }

      if (more) WRITE_VT(cur ^ 1);

      const char* vsm = (const char*)&Vtsm[cur][0];
#pragma unroll
      for (int k2 = 0; k2 < 2; ++k2) {
        const int cb = k2 * 64 + hi * 16;
        const v8bf aP = *(const v8bf*)((const char*)&Psm[w][0] + lo * 128 + (cb ^ ((lo & 7) << 4)));
#pragma unroll
        for (int n = 0; n < 8; ++n) {
          const int r = n * 16 + lo;
          const v8bf bv = *(const v8bf*)(vsm + r * 128 + (cb ^ ((r & 7) << 4)));
          accO[n] = __builtin_amdgcn_mfma_f32_16x16x32_bf16(aP, bv, accO[n], 0, 0, 0);
        }
      }
      if (more) __syncthreads();
    }
  }

  // store partials: unnormalized O (bf16), m, l
#pragma unroll
  for (int r = 0; r < 4; ++r) {
    const int qr = q0 + w * 16 + hi * 4 + r;
    __bf16* op = Opart + ((size_t)s * NROWS + b * SEQ + qr) * HD + lo;
#pragma unroll
    for (int n = 0; n < 8; ++n) op[n * 16] = (__bf16)accO[n][r];
    if (lo == 0) {
      float* mlp = Ml + ((size_t)s * NROWS + b * SEQ + qr) * 2;
      mlp[0] = m_s[r];
      mlp[1] = l_s[r];
    }
  }
}

// ---------------- combine the four KV-chunk partials ----------------
__global__ __launch_bounds__(256) void combine_kernel(
    const __bf16* __restrict__ Opart, const float* __restrict__ Ml,
    float* __restrict__ out)
{
  const int idx = blockIdx.x * 256 + threadIdx.x;  // 0..65535
  const int row = idx >> 2, ch = idx & 3;          // 32-col chunk
  float m[4], l[4];
#pragma unroll
  for (int s = 0; s < 4; ++s) {
    const float* mlp = Ml + ((size_t)s * NROWS + row) * 2;
    m[s] = mlp[0];
    l[s] = mlp[1];
  }
  const float M = fmaxf(fmaxf(m[0], m[1]), fmaxf(m[2], m[3]));
  float e[4], denom = 0.f;
#pragma unroll
  for (int s = 0; s < 4; ++s) { e[s] = __expf(m[s] - M); denom += l[s] * e[s]; }
  const float inv = 1.f / denom;

  float* po = out + (size_t)row * HD + ch * 32;
#pragma unroll
  for (int j = 0; j < 4; ++j) {     // 4 groups of 8 cols
    float sum[8];
#pragma unroll
    for (int q2 = 0; q2 < 8; ++q2) sum[q2] = 0.f;
#pragma unroll
    for (int s = 0; s < 4; ++s) {
      U8 o;
      o.v = *(const v8bf*)(Opart + ((size_t)s * NROWS + row) * HD + ch * 32 + j * 8);
#pragma unroll
      for (int q2 = 0; q2 < 8; ++q2) sum[q2] += (float)o.b[q2] * e[s];
    }
#pragma unroll
    for (int q2 = 0; q2 < 8; ++q2) po[j * 8 + q2] = sum[q2] * inv;
  }
}

extern "C" void kernel_launch(void* const* d_in, const int* in_sizes, int n_in,
                              void* d_out, int out_size, void* d_ws, size_t ws_size,
                              hipStream_t stream) {
  const float* x  = (const float*)d_in[0];
  const float* Wq = (const float*)d_in[1];
  const float* bq = (const float*)d_in[2];
  const float* Wk = (const float*)d_in[3];
  const float* bk = (const float*)d_in[4];
  const float* Wv = (const float*)d_in[5];
  const float* bv = (const float*)d_in[6];
  float* out = (float*)d_out;

  // workspace (~30 MiB)
  __bf16* Qb = (__bf16*)d_ws;                        // 16384x128 bf16 each
  __bf16* Kb = Qb + (size_t)NROWS * HD;
  __bf16* Vb = Kb + (size_t)NROWS * HD;
  __bf16* Wb = Vb + (size_t)NROWS * HD;              // 3 x 128 x 2048 bf16
  __bf16* Opart = Wb + (size_t)3 * HD * NEMB;        // 4 x 16384 x 128 bf16
  float*  Ml = (float*)(Opart + (size_t)4 * NROWS * HD);  // 4 x 16384 x 2 fp32

  wconv_kernel<<<dim3(3 * 64), dim3(256), 0, stream>>>(Wq, Wk, Wv, Wb);
  qkv_proj_kernel<<<dim3(128 * 3), dim3(256), 0, stream>>>(
      x, Wb, bq, bk, bv, Qb, Kb, Vb);
  attn_kernel<<<dim3(BATCH * 32 * 4), dim3(256), 0, stream>>>(Qb, Kb, Vb, Opart, Ml);
  combine_kernel<<<dim3(NROWS * 4 / 256), dim3(256), 0, stream>>>(Opart, Ml, out);
}